// Round 4
// baseline (670.987 us; speedup 1.0000x reference)
//
#include <hip/hip_runtime.h>
#include <math.h>

typedef unsigned short u16;
typedef __attribute__((ext_vector_type(8))) short bfrag;     // 8 bf16 = 4 VGPRs
typedef __attribute__((ext_vector_type(4))) float f32x4;     // MFMA acc
typedef __attribute__((ext_vector_type(4))) unsigned short us4;

#define B_SZ 32
#define L_SZ 3136
#define C_SZ 256
#define NHEADS 8
#define HID_SZ 1024
#define NW 49
#define NWIN 64
#define SHIFT 24
#define M_SZ (B_SZ * L_SZ)          // 100352
#define MCH (M_SZ / 4)              // 25088 rows per chunk
#define WCH (B_SZ * NWIN / 4)       // 512 windows per chunk
#define SCALEF 0.17677669529663687f // (256/8)^-0.5

__device__ __forceinline__ float bf2f(u16 u) {
  union { unsigned int i; float f; } v; v.i = ((unsigned)u) << 16; return v.f;
}
__device__ __forceinline__ u16 f2bf(float f) {
  union { unsigned int i; float f; } v; v.f = f;
  return (u16)((v.i + 0x7fffu + ((v.i >> 16) & 1u)) >> 16);
}
// dual-dtype scalar read: flag=1 -> buffer is f32, flag=0 -> bf16
__device__ __forceinline__ float rdin(const void* p, size_t i, int flag) {
  return flag ? ((const float*)p)[i] : bf2f(((const u16*)p)[i]);
}

// ---- input dtype detection: f32 data read as bf16 shows huge/NaN values -----
__global__ void detect_kernel(const u16* __restrict__ x, int* __restrict__ flag) {
  if (threadIdx.x == 0) {
    int f = 0;
    for (int i = 0; i < 2048; ++i) {
      float v = bf2f(x[i]);
      if (!(fabsf(v) < 1e10f)) { f = 1; break; }  // catches NaN too
    }
    *flag = f;
  }
}

// ---------------- weight transpose: (K,N) -> (N,K) row-major, emit bf16 ------
__global__ void transpose_kernel(const void* __restrict__ in, u16* __restrict__ out,
                                 int K, int N, const int* __restrict__ flagp) {
  const int idx = blockIdx.x * 256 + threadIdx.x;
  if (idx >= K * N) return;
  const int flag = *flagp;
  const int n = idx / K;
  const int k = idx - n * K;
  out[idx] = f2bf(rdin(in, (size_t)k * N + n, flag));
}

// ---------------- relative-position bias gather: (64,8,49,49) f32 ------------
__global__ void bias_kernel(const void* __restrict__ tab, const int* __restrict__ rel,
                            float* __restrict__ bm, const int* __restrict__ flagp) {
  const int idx = blockIdx.x * 256 + threadIdx.x;
  const int tot = NWIN * NHEADS * NW * NW;
  if (idx >= tot) return;
  const int flag = *flagp;
  const int w = idx / (NHEADS * NW * NW);
  const int r = idx - w * (NHEADS * NW * NW);
  const int h = r / (NW * NW);
  const int ij = r - h * (NW * NW);
  bm[idx] = rdin(tab, (size_t)rel[w * NW * NW + ij] * NHEADS + h, flag);
}

// ---------------- LayerNorm1 (dual-dtype in) fused with +SHIFT roll ----------
__global__ __launch_bounds__(256) void ln1_kernel(
    const void* __restrict__ x, const void* __restrict__ w,
    const void* __restrict__ b, u16* __restrict__ out,
    const int* __restrict__ flagp) {
  const int flag = *flagp;
  const int row = blockIdx.x * 4 + (threadIdx.x >> 6);
  const int lane = threadIdx.x & 63;
  float v[4];
  if (flag) {
    const float4 u = *((const float4*)x + (size_t)row * 64 + lane);
    v[0] = u.x; v[1] = u.y; v[2] = u.z; v[3] = u.w;
  } else {
    const us4 u = *(const us4*)((const u16*)x + (size_t)row * C_SZ + lane * 4);
#pragma unroll
    for (int j = 0; j < 4; ++j) v[j] = bf2f(u[j]);
  }
  float s = 0.f, sq = 0.f;
#pragma unroll
  for (int j = 0; j < 4; ++j) { s += v[j]; sq += v[j] * v[j]; }
#pragma unroll
  for (int d = 1; d < 64; d <<= 1) { s += __shfl_xor(s, d); sq += __shfl_xor(sq, d); }
  const float mu = s * (1.0f / C_SZ);
  const float rs = rsqrtf(sq * (1.0f / C_SZ) - mu * mu + 1e-5f);
  const int bb = row / L_SZ;
  int l2 = row - bb * L_SZ + SHIFT;
  if (l2 >= L_SZ) l2 -= L_SZ;
  u16* o = out + ((size_t)bb * L_SZ + l2) * C_SZ + lane * 4;
  us4 ov;
#pragma unroll
  for (int j = 0; j < 4; ++j) {
    const int c = lane * 4 + j;
    ov[j] = f2bf((v[j] - mu) * rs * rdin(w, c, flag) + rdin(b, c, flag));
  }
  *(us4*)o = ov;
}

// ---------------- LayerNorm2 (bf16 x2 in), dual-dtype w/b --------------------
__global__ __launch_bounds__(256) void ln2_kernel(
    const u16* __restrict__ x, const void* __restrict__ w,
    const void* __restrict__ b, u16* __restrict__ out,
    const int* __restrict__ flagp) {
  const int flag = *flagp;
  const int row = blockIdx.x * 4 + (threadIdx.x >> 6);
  const int lane = threadIdx.x & 63;
  const us4 u = *(const us4*)(x + (size_t)row * C_SZ + lane * 4);
  float v[4];
#pragma unroll
  for (int j = 0; j < 4; ++j) v[j] = bf2f(u[j]);
  float s = 0.f, sq = 0.f;
#pragma unroll
  for (int j = 0; j < 4; ++j) { s += v[j]; sq += v[j] * v[j]; }
#pragma unroll
  for (int d = 1; d < 64; d <<= 1) { s += __shfl_xor(s, d); sq += __shfl_xor(sq, d); }
  const float mu = s * (1.0f / C_SZ);
  const float rs = rsqrtf(sq * (1.0f / C_SZ) - mu * mu + 1e-5f);
  u16* o = out + (size_t)row * C_SZ + lane * 4;
  us4 ov;
#pragma unroll
  for (int j = 0; j < 4; ++j) {
    const int c = lane * 4 + j;
    ov[j] = f2bf((v[j] - mu) * rs * rdin(w, c, flag) + rdin(b, c, flag));
  }
  *(us4*)o = ov;
}

// ---------------- tiled MFMA GEMM: C = A(MxK) * Bt(NxK)^T + bias -------------
// MODE 0: store bf16                 MODE 1: proj (un-roll + x residual -> bf16 x2)
// MODE 2: exact GELU, bf16           MODE 3: + bf16 residual -> *** f32 d_out ***
// MODE 1 must be launched over the FULL M (uses absolute rows for the un-roll);
// other modes are chunk-local.
#define BM 128
#define BN 128
#define BKT 64

template <int MODE>
__global__ __launch_bounds__(256, 2) void gemm_kernel(
    const u16* __restrict__ A, const u16* __restrict__ Bt,
    const void* __restrict__ bias, int N, int K, void* __restrict__ Cout,
    const void* __restrict__ resx, const u16* __restrict__ resb2,
    const int* __restrict__ flagp) {
  __shared__ u16 Als[BM * BKT];  // chunk-XOR-swizzled: elem = r*64 + (kc^(r&7))*8
  __shared__ u16 Bls[BN * BKT];
  const int flag = *flagp;
  const int tid = threadIdx.x;
  const int lane = tid & 63;
  const int lr = lane & 15;
  const int lg = lane >> 4;
  const int m0 = blockIdx.y * BM;
  const int n0 = blockIdx.x * BN;
  const int wid = tid >> 6;
  const int wm = (wid >> 1) * 64;
  const int wn = (wid & 1) * 64;
  const int srow = tid >> 3;  // 0..31
  const int skc = tid & 7;    // k-chunk 0..7

  const f32x4 fzero = {0.f, 0.f, 0.f, 0.f};
  f32x4 acc[4][4];
#pragma unroll
  for (int i = 0; i < 4; ++i)
#pragma unroll
    for (int j = 0; j < 4; ++j) acc[i][j] = fzero;

  const u16* Ag = A + (size_t)m0 * K + skc * 8;
  const u16* Bg = Bt + (size_t)n0 * K + skc * 8;

  for (int k0 = 0; k0 < K; k0 += BKT) {
#pragma unroll
    for (int j = 0; j < 4; ++j) {
      const int r = srow + j * 32;
      const int ph = (skc ^ (r & 7)) * 8;
      bfrag av = *(const bfrag*)(Ag + (size_t)r * K + k0);
      bfrag bv = *(const bfrag*)(Bg + (size_t)r * K + k0);
      *(bfrag*)(Als + r * 64 + ph) = av;
      *(bfrag*)(Bls + r * 64 + ph) = bv;
    }
    __syncthreads();
#pragma unroll
    for (int s = 0; s < 2; ++s) {
      const int kg = s * 4 + lg;
      bfrag af[4], bfv[4];
#pragma unroll
      for (int m = 0; m < 4; ++m) {
        const int r = wm + m * 16 + lr;
        af[m] = *(const bfrag*)(Als + r * 64 + ((kg ^ (r & 7)) * 8));
      }
#pragma unroll
      for (int n = 0; n < 4; ++n) {
        const int r = wn + n * 16 + lr;
        bfv[n] = *(const bfrag*)(Bls + r * 64 + ((kg ^ (r & 7)) * 8));
      }
#pragma unroll
      for (int m = 0; m < 4; ++m)
#pragma unroll
        for (int n = 0; n < 4; ++n)
          acc[m][n] = __builtin_amdgcn_mfma_f32_16x16x32_bf16(af[m], bfv[n],
                                                              acc[m][n], 0, 0, 0);
    }
    __syncthreads();
  }

  float bv4[4];
#pragma unroll
  for (int n = 0; n < 4; ++n) bv4[n] = rdin(bias, n0 + wn + n * 16 + lr, flag);

#pragma unroll
  for (int m = 0; m < 4; ++m) {
#pragma unroll
    for (int i = 0; i < 4; ++i) {
      const int row = m0 + wm + m * 16 + lg * 4 + i;
      if (MODE == 1) {
        const int bb = row / L_SZ;
        int l2 = row - bb * L_SZ - SHIFT;
        if (l2 < 0) l2 += L_SZ;
        const size_t orow = (size_t)bb * L_SZ + l2;
#pragma unroll
        for (int n = 0; n < 4; ++n) {
          const int col = n0 + wn + n * 16 + lr;
          ((u16*)Cout)[orow * N + col] =
              f2bf(rdin(resx, orow * N + col, flag) + acc[m][n][i] + bv4[n]);
        }
      } else {
#pragma unroll
        for (int n = 0; n < 4; ++n) {
          const int col = n0 + wn + n * 16 + lr;
          float v = acc[m][n][i] + bv4[n];
          if (MODE == 2) v = 0.5f * v * (1.0f + erff(v * 0.70710678f));
          if (MODE == 3) {
            v += bf2f(resb2[(size_t)row * N + col]);
            ((float*)Cout)[(size_t)row * N + col] = v;   // f32 final output
          } else {
            ((u16*)Cout)[(size_t)row * N + col] = f2bf(v);
          }
        }
      }
    }
  }
}

// ---------------- windowed attention: 1 block / window, wave = 2 heads -------
// qkv/out are CHUNK-LOCAL pointers; widx0 = global window offset of the chunk.
__global__ __launch_bounds__(256) void attn_kernel(const u16* __restrict__ qkv,
                                                   const float* __restrict__ bm,
                                                   u16* __restrict__ out, int widx0) {
  __shared__ u16 Pls[4][64 * 72];  // per-wave P tile, stride 72 (144B = 9x16B)
  const int wl = blockIdx.x;             // local window
  const int w = (widx0 + wl) & (NWIN - 1);
  const int wv = threadIdx.x >> 6;
  const int lane = threadIdx.x & 63;
  const int lr = lane & 15;
  const int lg = lane >> 4;
  const size_t base = (size_t)wl * NW;   // chunk-local rows
  u16* P = Pls[wv];
  const f32x4 fzero = {0.f, 0.f, 0.f, 0.f};

  for (int rep = 0; rep < 2; ++rep) {
    const int h = wv * 2 + rep;
    bfrag qf[4], kf[4];
#pragma unroll
    for (int m = 0; m < 4; ++m) {
      int r = m * 16 + lr; if (r > NW - 1) r = NW - 1;  // clamp pad rows
      qf[m] = *(const bfrag*)(qkv + (base + r) * 768 + h * 32 + lg * 8);
      kf[m] = *(const bfrag*)(qkv + (base + r) * 768 + 256 + h * 32 + lg * 8);
    }
    f32x4 s[4][4];
#pragma unroll
    for (int m = 0; m < 4; ++m)
#pragma unroll
      for (int n = 0; n < 4; ++n)
        s[m][n] = __builtin_amdgcn_mfma_f32_16x16x32_bf16(qf[m], kf[n], fzero, 0, 0, 0);

    const float* bh = bm + (size_t)(w * NHEADS + h) * (NW * NW);
#pragma unroll
    for (int m = 0; m < 4; ++m) {
#pragma unroll
      for (int i = 0; i < 4; ++i) {
        const int row = m * 16 + lg * 4 + i;
        const int brow = row > NW - 1 ? NW - 1 : row;
        float vals[4];
#pragma unroll
        for (int n = 0; n < 4; ++n) {
          const int c = n * 16 + lr;
          vals[n] = (c < NW) ? (s[m][n][i] * SCALEF + bh[brow * NW + c]) : -1e30f;
        }
        float mx = fmaxf(fmaxf(vals[0], vals[1]), fmaxf(vals[2], vals[3]));
#pragma unroll
        for (int d = 1; d < 16; d <<= 1) mx = fmaxf(mx, __shfl_xor(mx, d));
        float sum = 0.f;
#pragma unroll
        for (int n = 0; n < 4; ++n) { vals[n] = __expf(vals[n] - mx); sum += vals[n]; }
#pragma unroll
        for (int d = 1; d < 16; d <<= 1) sum += __shfl_xor(sum, d);
        const float inv = 1.0f / sum;
#pragma unroll
        for (int n = 0; n < 4; ++n)
          P[row * 72 + n * 16 + lr] = f2bf(vals[n] * inv);
      }
    }
    // PV
    f32x4 o[4][2];
#pragma unroll
    for (int m = 0; m < 4; ++m) { o[m][0] = fzero; o[m][1] = fzero; }
#pragma unroll
    for (int s2 = 0; s2 < 2; ++s2) {
      bfrag pf[4];
#pragma unroll
      for (int m = 0; m < 4; ++m)
        pf[m] = *(const bfrag*)(P + (m * 16 + lr) * 72 + s2 * 32 + lg * 8);
#pragma unroll
      for (int n = 0; n < 2; ++n) {
        bfrag vf;
#pragma unroll
        for (int i = 0; i < 8; ++i) {
          int kk = s2 * 32 + lg * 8 + i; if (kk > NW - 1) kk = NW - 1;  // P==0 past 48
          vf[i] = *(const short*)(qkv + (base + kk) * 768 + 512 + h * 32 + n * 16 + lr);
        }
#pragma unroll
        for (int m = 0; m < 4; ++m)
          o[m][n] = __builtin_amdgcn_mfma_f32_16x16x32_bf16(pf[m], vf, o[m][n], 0, 0, 0);
      }
    }
#pragma unroll
    for (int m = 0; m < 4; ++m)
#pragma unroll
      for (int i = 0; i < 4; ++i) {
        const int row = m * 16 + lg * 4 + i;
        if (row < NW) {
#pragma unroll
          for (int n = 0; n < 2; ++n)
            out[(base + row) * C_SZ + h * 32 + n * 16 + lr] = f2bf(o[m][n][i]);
        }
      }
  }
}

// -----------------------------------------------------------------------------
extern "C" void kernel_launch(void* const* d_in, const int* in_sizes, int n_in,
                              void* d_out, int out_size, void* d_ws, size_t ws_size,
                              hipStream_t stream) {
  (void)in_sizes; (void)n_in; (void)out_size; (void)ws_size;
  const void* x     = d_in[0];
  const void* qkvw  = d_in[1];
  const void* qkvb  = d_in[2];
  const void* projw = d_in[3];
  const void* projb = d_in[4];
  const void* btab  = d_in[5];
  const void* n1w   = d_in[6];
  const void* n1b   = d_in[7];
  const void* n2w   = d_in[8];
  const void* n2b   = d_in[9];
  const void* fc1w  = d_in[10];
  const void* fc1b  = d_in[11];
  const void* fc2w  = d_in[12];
  const void* fc2b  = d_in[13];
  const int* rel    = (const int*)d_in[14];

  // ---- workspace: 153.2 MiB total
  char* ws = (char*)d_ws;
  size_t off = 0;
  auto alloc = [&](size_t bytes) -> char* {
    char* p = ws + off; off += (bytes + 255) & ~(size_t)255; return p;
  };
  int* flagp    = (int*)alloc(256);
  u16* qkvwT    = (u16*)alloc((size_t)768 * 256 * 2);
  u16* projwT   = (u16*)alloc((size_t)256 * 256 * 2);
  u16* fc1wT    = (u16*)alloc((size_t)1024 * 256 * 2);
  u16* fc2wT    = (u16*)alloc((size_t)256 * 1024 * 2);
  float* biasm  = (float*)alloc((size_t)NWIN * NHEADS * NW * NW * 4);
  u16* bufh     = (u16*)alloc((size_t)M_SZ * C_SZ * 2);   // h / attn-out / h2
  u16* x2b      = (u16*)alloc((size_t)M_SZ * C_SZ * 2);   // bf16 residual x2
  u16* scratch2 = (u16*)alloc((size_t)MCH * HID_SZ * 2);  // qkv chunk / fc1 chunk

  detect_kernel<<<1, 64, 0, stream>>>((const u16*)x, flagp);
  transpose_kernel<<<(256 * 768 + 255) / 256, 256, 0, stream>>>(qkvw, qkvwT, 256, 768, flagp);
  transpose_kernel<<<(256 * 256 + 255) / 256, 256, 0, stream>>>(projw, projwT, 256, 256, flagp);
  transpose_kernel<<<(256 * 1024 + 255) / 256, 256, 0, stream>>>(fc1w, fc1wT, 256, 1024, flagp);
  transpose_kernel<<<(1024 * 256 + 255) / 256, 256, 0, stream>>>(fc2w, fc2wT, 1024, 256, flagp);
  bias_kernel<<<(NWIN * NHEADS * NW * NW + 255) / 256, 256, 0, stream>>>(btab, rel, biasm, flagp);

  ln1_kernel<<<M_SZ / 4, 256, 0, stream>>>(x, n1w, n1b, bufh, flagp);

  // qkv + attention, 4 chunks of 25088 rows / 512 windows, sharing scratch2
  for (int c = 0; c < 4; ++c) {
    const size_t roff = (size_t)c * MCH;
    gemm_kernel<0><<<dim3(768 / BN, MCH / BM), 256, 0, stream>>>(
        bufh + roff * C_SZ, qkvwT, qkvb, 768, 256, scratch2, nullptr, nullptr, flagp);
    attn_kernel<<<WCH, 256, 0, stream>>>(scratch2, biasm, bufh + roff * C_SZ, c * WCH);
  }

  // proj + un-roll + x residual -> bf16 x2 (full M: needs absolute rows)
  gemm_kernel<1><<<dim3(256 / BN, M_SZ / BM), 256, 0, stream>>>(
      bufh, projwT, projb, 256, 256, x2b, x, nullptr, flagp);

  // MLP, 4 chunks of 25088 rows; final fc2 writes f32 to d_out
  for (int q = 0; q < 4; ++q) {
    const size_t roff = (size_t)q * MCH;
    ln2_kernel<<<MCH / 4, 256, 0, stream>>>(x2b + roff * C_SZ, n2w, n2b,
                                            bufh + roff * C_SZ, flagp);
    gemm_kernel<2><<<dim3(1024 / BN, MCH / BM), 256, 0, stream>>>(
        bufh + roff * C_SZ, fc1wT, fc1b, 1024, 256, scratch2, nullptr, nullptr, flagp);
    gemm_kernel<3><<<dim3(256 / BN, MCH / BM), 256, 0, stream>>>(
        scratch2, fc2wT, fc2b, 256, 1024, (float*)d_out + roff * C_SZ,
        nullptr, x2b + roff * C_SZ, flagp);
  }
}

// Round 5
// 511.065 us; speedup vs baseline: 1.3129x; 1.3129x over previous
//
#include <hip/hip_runtime.h>
#include <math.h>

typedef unsigned short u16;
typedef __attribute__((ext_vector_type(8))) short bfrag;     // 8 bf16 = 4 VGPRs
typedef __attribute__((ext_vector_type(4))) float f32x4;     // MFMA acc
typedef __attribute__((ext_vector_type(4))) unsigned short us4;

#define B_SZ 32
#define L_SZ 3136
#define C_SZ 256
#define NHEADS 8
#define HID_SZ 1024
#define NW 49
#define NWIN 64
#define SHIFT 24
#define M_SZ (B_SZ * L_SZ)          // 100352
#define SCALEF 0.17677669529663687f // (256/8)^-0.5

__device__ __forceinline__ float bf2f(u16 u) {
  union { unsigned int i; float f; } v; v.i = ((unsigned)u) << 16; return v.f;
}
__device__ __forceinline__ u16 f2bf(float f) {
  union { unsigned int i; float f; } v; v.f = f;
  return (u16)((v.i + 0x7fffu + ((v.i >> 16) & 1u)) >> 16);
}
// async global->LDS, 16B per lane; LDS dest = wave-uniform base + lane*16
__device__ __forceinline__ void gload_lds16(const u16* g, u16* l) {
  __builtin_amdgcn_global_load_lds(
      (const __attribute__((address_space(1))) unsigned int*)g,
      (__attribute__((address_space(3))) unsigned int*)l, 16, 0, 0);
}

// ---------------- weight transpose: (K,N) f32 -> (N,K) bf16 row-major --------
__global__ void transpose_kernel(const float* __restrict__ in, u16* __restrict__ out,
                                 int K, int N) {
  const int idx = blockIdx.x * 256 + threadIdx.x;
  if (idx >= K * N) return;
  const int n = idx / K;
  const int k = idx - n * K;
  out[idx] = f2bf(in[(size_t)k * N + n]);
}

// ---------------- relative-position bias gather: (64,8,49,49) f32 ------------
__global__ void bias_kernel(const float* __restrict__ tab, const int* __restrict__ rel,
                            float* __restrict__ bm) {
  const int idx = blockIdx.x * 256 + threadIdx.x;
  const int tot = NWIN * NHEADS * NW * NW;
  if (idx >= tot) return;
  const int w = idx / (NHEADS * NW * NW);
  const int r = idx - w * (NHEADS * NW * NW);
  const int h = r / (NW * NW);
  const int ij = r - h * (NW * NW);
  bm[idx] = tab[(size_t)rel[w * NW * NW + ij] * NHEADS + h];
}

// ---------------- LayerNorm1 (f32 in) + +SHIFT roll; 4 rows/wave for ILP -----
__global__ __launch_bounds__(256) void ln1_kernel(
    const float* __restrict__ x, const float* __restrict__ w,
    const float* __restrict__ b, u16* __restrict__ out) {
  const int wv = threadIdx.x >> 6;
  const int lane = threadIdx.x & 63;
  const int row0 = blockIdx.x * 16 + wv * 4;
  float4 u[4];
#pragma unroll
  for (int r = 0; r < 4; ++r)
    u[r] = *((const float4*)x + (size_t)(row0 + r) * 64 + lane);
  float s[4], sq[4];
#pragma unroll
  for (int r = 0; r < 4; ++r) {
    s[r]  = u[r].x + u[r].y + u[r].z + u[r].w;
    sq[r] = u[r].x * u[r].x + u[r].y * u[r].y + u[r].z * u[r].z + u[r].w * u[r].w;
  }
#pragma unroll
  for (int d = 1; d < 64; d <<= 1)
#pragma unroll
    for (int r = 0; r < 4; ++r) {
      s[r] += __shfl_xor(s[r], d); sq[r] += __shfl_xor(sq[r], d);
    }
  float wv4[4], bv4[4];
#pragma unroll
  for (int j = 0; j < 4; ++j) { wv4[j] = w[lane * 4 + j]; bv4[j] = b[lane * 4 + j]; }
#pragma unroll
  for (int r = 0; r < 4; ++r) {
    const int row = row0 + r;
    const float mu = s[r] * (1.0f / C_SZ);
    const float rs = rsqrtf(sq[r] * (1.0f / C_SZ) - mu * mu + 1e-5f);
    const int bb = row / L_SZ;
    int l2 = row - bb * L_SZ + SHIFT;
    if (l2 >= L_SZ) l2 -= L_SZ;
    const float vv[4] = {u[r].x, u[r].y, u[r].z, u[r].w};
    us4 ov;
#pragma unroll
    for (int j = 0; j < 4; ++j) ov[j] = f2bf((vv[j] - mu) * rs * wv4[j] + bv4[j]);
    *(us4*)(out + ((size_t)bb * L_SZ + l2) * C_SZ + lane * 4) = ov;
  }
}

// ---------------- LayerNorm2 (bf16 in), no roll; 4 rows/wave -----------------
__global__ __launch_bounds__(256) void ln2_kernel(
    const u16* __restrict__ x, const float* __restrict__ w,
    const float* __restrict__ b, u16* __restrict__ out) {
  const int wv = threadIdx.x >> 6;
  const int lane = threadIdx.x & 63;
  const int row0 = blockIdx.x * 16 + wv * 4;
  us4 u[4];
#pragma unroll
  for (int r = 0; r < 4; ++r)
    u[r] = *(const us4*)(x + (size_t)(row0 + r) * C_SZ + lane * 4);
  float v[4][4], s[4], sq[4];
#pragma unroll
  for (int r = 0; r < 4; ++r) {
    s[r] = 0.f; sq[r] = 0.f;
#pragma unroll
    for (int j = 0; j < 4; ++j) {
      v[r][j] = bf2f(u[r][j]); s[r] += v[r][j]; sq[r] += v[r][j] * v[r][j];
    }
  }
#pragma unroll
  for (int d = 1; d < 64; d <<= 1)
#pragma unroll
    for (int r = 0; r < 4; ++r) {
      s[r] += __shfl_xor(s[r], d); sq[r] += __shfl_xor(sq[r], d);
    }
  float wv4[4], bv4[4];
#pragma unroll
  for (int j = 0; j < 4; ++j) { wv4[j] = w[lane * 4 + j]; bv4[j] = b[lane * 4 + j]; }
#pragma unroll
  for (int r = 0; r < 4; ++r) {
    const float mu = s[r] * (1.0f / C_SZ);
    const float rs = rsqrtf(sq[r] * (1.0f / C_SZ) - mu * mu + 1e-5f);
    us4 ov;
#pragma unroll
    for (int j = 0; j < 4; ++j) ov[j] = f2bf((v[r][j] - mu) * rs * wv4[j] + bv4[j]);
    *(us4*)(out + (size_t)(row0 + r) * C_SZ + lane * 4) = ov;
  }
}

// ---------------- tiled MFMA GEMM: C = A(MxK) * Bt(NxK)^T + bias -------------
// Staging: global_load_lds 16B/lane, LDS linear, XOR-swizzle folded into the
// per-lane GLOBAL source address (rule: inverse-swz source + swz read).
// LDS elem (r, kc) holds global chunk kc^(r&7); read side uses kg^(r&7).
// MODE 0: store bf16                 MODE 1: proj (un-roll + x residual -> bf16)
// MODE 2: exact GELU, bf16           MODE 3: + bf16 residual -> f32 d_out
#define BM 128
#define BN 128
#define BKT 64

template <int MODE>
__global__ __launch_bounds__(256, 2) void gemm_kernel(
    const u16* __restrict__ A, const u16* __restrict__ Bt,
    const float* __restrict__ bias, int N, int K, void* __restrict__ Cout,
    const float* __restrict__ resx, const u16* __restrict__ resb2) {
  __shared__ u16 Als[BM * BKT];
  __shared__ u16 Bls[BN * BKT];
  const int tid = threadIdx.x;
  const int lane = tid & 63;
  const int lr = lane & 15;
  const int lg = lane >> 4;
  const int m0 = blockIdx.y * BM;
  const int n0 = blockIdx.x * BN;
  const int wid = tid >> 6;
  const int wm = (wid >> 1) * 64;
  const int wn = (wid & 1) * 64;

  // staging geometry: wave wid covers rows [wid*32, wid*32+32), 4 groups of 8
  const int grow = lane >> 3;              // row within 8-row group
  const int gch = (lane & 7) ^ grow;       // pre-swizzled source k-chunk

  const f32x4 fzero = {0.f, 0.f, 0.f, 0.f};
  f32x4 acc[4][4];
#pragma unroll
  for (int i = 0; i < 4; ++i)
#pragma unroll
    for (int j = 0; j < 4; ++j) acc[i][j] = fzero;

  const u16* Agl = A + (size_t)m0 * K + gch * 8;
  const u16* Bgl = Bt + (size_t)n0 * K + gch * 8;

  for (int k0 = 0; k0 < K; k0 += BKT) {
#pragma unroll
    for (int g = 0; g < 4; ++g) {
      const int rbase = wid * 32 + g * 8;
      gload_lds16(Agl + (size_t)(rbase + grow) * K + k0, Als + rbase * 64);
      gload_lds16(Bgl + (size_t)(rbase + grow) * K + k0, Bls + rbase * 64);
    }
    __syncthreads();   // compiler inserts s_waitcnt vmcnt(0) before barrier
#pragma unroll
    for (int s = 0; s < 2; ++s) {
      const int kg = s * 4 + lg;
      bfrag af[4], bfv[4];
#pragma unroll
      for (int m = 0; m < 4; ++m) {
        const int r = wm + m * 16 + lr;
        af[m] = *(const bfrag*)(Als + r * 64 + ((kg ^ (r & 7)) * 8));
      }
#pragma unroll
      for (int n = 0; n < 4; ++n) {
        const int r = wn + n * 16 + lr;
        bfv[n] = *(const bfrag*)(Bls + r * 64 + ((kg ^ (r & 7)) * 8));
      }
#pragma unroll
      for (int m = 0; m < 4; ++m)
#pragma unroll
        for (int n = 0; n < 4; ++n)
          acc[m][n] = __builtin_amdgcn_mfma_f32_16x16x32_bf16(af[m], bfv[n],
                                                              acc[m][n], 0, 0, 0);
    }
    __syncthreads();
  }

  float bv4[4];
#pragma unroll
  for (int n = 0; n < 4; ++n) bv4[n] = bias[n0 + wn + n * 16 + lr];

#pragma unroll
  for (int m = 0; m < 4; ++m) {
#pragma unroll
    for (int i = 0; i < 4; ++i) {
      const int row = m0 + wm + m * 16 + lg * 4 + i;
      if (MODE == 1) {
        const int bb = row / L_SZ;
        int l2 = row - bb * L_SZ - SHIFT;
        if (l2 < 0) l2 += L_SZ;
        const size_t orow = (size_t)bb * L_SZ + l2;
#pragma unroll
        for (int n = 0; n < 4; ++n) {
          const int col = n0 + wn + n * 16 + lr;
          ((u16*)Cout)[orow * N + col] =
              f2bf(resx[orow * N + col] + acc[m][n][i] + bv4[n]);
        }
      } else {
#pragma unroll
        for (int n = 0; n < 4; ++n) {
          const int col = n0 + wn + n * 16 + lr;
          float v = acc[m][n][i] + bv4[n];
          if (MODE == 2) v = 0.5f * v * (1.0f + erff(v * 0.70710678f));
          if (MODE == 3) {
            v += bf2f(resb2[(size_t)row * N + col]);
            ((float*)Cout)[(size_t)row * N + col] = v;   // f32 final output
          } else {
            ((u16*)Cout)[(size_t)row * N + col] = f2bf(v);
          }
        }
      }
    }
  }
}

// ---------------- windowed attention: 1 block / window, wave = 2 heads -------
__global__ __launch_bounds__(256) void attn_kernel(const u16* __restrict__ qkv,
                                                   const float* __restrict__ bm,
                                                   u16* __restrict__ out, int widx0) {
  __shared__ u16 Pls[4][64 * 72];  // per-wave P tile, stride 72 (144B = 9x16B)
  const int wl = blockIdx.x;             // chunk-local window
  const int w = (widx0 + wl) & (NWIN - 1);
  const int wv = threadIdx.x >> 6;
  const int lane = threadIdx.x & 63;
  const int lr = lane & 15;
  const int lg = lane >> 4;
  const size_t base = (size_t)wl * NW;   // chunk-local rows
  u16* P = Pls[wv];
  const f32x4 fzero = {0.f, 0.f, 0.f, 0.f};

  for (int rep = 0; rep < 2; ++rep) {
    const int h = wv * 2 + rep;
    bfrag qf[4], kf[4];
#pragma unroll
    for (int m = 0; m < 4; ++m) {
      int r = m * 16 + lr; if (r > NW - 1) r = NW - 1;  // clamp pad rows
      qf[m] = *(const bfrag*)(qkv + (base + r) * 768 + h * 32 + lg * 8);
      kf[m] = *(const bfrag*)(qkv + (base + r) * 768 + 256 + h * 32 + lg * 8);
    }
    f32x4 s[4][4];
#pragma unroll
    for (int m = 0; m < 4; ++m)
#pragma unroll
      for (int n = 0; n < 4; ++n)
        s[m][n] = __builtin_amdgcn_mfma_f32_16x16x32_bf16(qf[m], kf[n], fzero, 0, 0, 0);

    const float* bh = bm + (size_t)(w * NHEADS + h) * (NW * NW);
#pragma unroll
    for (int m = 0; m < 4; ++m) {
#pragma unroll
      for (int i = 0; i < 4; ++i) {
        const int row = m * 16 + lg * 4 + i;
        const int brow = row > NW - 1 ? NW - 1 : row;
        float vals[4];
#pragma unroll
        for (int n = 0; n < 4; ++n) {
          const int c = n * 16 + lr;
          vals[n] = (c < NW) ? (s[m][n][i] * SCALEF + bh[brow * NW + c]) : -1e30f;
        }
        float mx = fmaxf(fmaxf(vals[0], vals[1]), fmaxf(vals[2], vals[3]));
#pragma unroll
        for (int d = 1; d < 16; d <<= 1) mx = fmaxf(mx, __shfl_xor(mx, d));
        float sum = 0.f;
#pragma unroll
        for (int n = 0; n < 4; ++n) { vals[n] = __expf(vals[n] - mx); sum += vals[n]; }
#pragma unroll
        for (int d = 1; d < 16; d <<= 1) sum += __shfl_xor(sum, d);
        const float inv = 1.0f / sum;
#pragma unroll
        for (int n = 0; n < 4; ++n)
          P[row * 72 + n * 16 + lr] = f2bf(vals[n] * inv);
      }
    }
    // PV
    f32x4 o[4][2];
#pragma unroll
    for (int m = 0; m < 4; ++m) { o[m][0] = fzero; o[m][1] = fzero; }
#pragma unroll
    for (int s2 = 0; s2 < 2; ++s2) {
      bfrag pf[4];
#pragma unroll
      for (int m = 0; m < 4; ++m)
        pf[m] = *(const bfrag*)(P + (m * 16 + lr) * 72 + s2 * 32 + lg * 8);
#pragma unroll
      for (int n = 0; n < 2; ++n) {
        bfrag vf;
#pragma unroll
        for (int i = 0; i < 8; ++i) {
          int kk = s2 * 32 + lg * 8 + i; if (kk > NW - 1) kk = NW - 1;  // P==0 past 48
          vf[i] = *(const short*)(qkv + (base + kk) * 768 + 512 + h * 32 + n * 16 + lr);
        }
#pragma unroll
        for (int m = 0; m < 4; ++m)
          o[m][n] = __builtin_amdgcn_mfma_f32_16x16x32_bf16(pf[m], vf, o[m][n], 0, 0, 0);
      }
    }
#pragma unroll
    for (int m = 0; m < 4; ++m)
#pragma unroll
      for (int i = 0; i < 4; ++i) {
        const int row = m * 16 + lg * 4 + i;
        if (row < NW) {
#pragma unroll
          for (int n = 0; n < 2; ++n)
            out[(base + row) * C_SZ + h * 32 + n * 16 + lr] = f2bf(o[m][n][i]);
        }
      }
  }
}

// -----------------------------------------------------------------------------
extern "C" void kernel_launch(void* const* d_in, const int* in_sizes, int n_in,
                              void* d_out, int out_size, void* d_ws, size_t ws_size,
                              hipStream_t stream) {
  (void)in_sizes; (void)n_in; (void)out_size;
  const float* x     = (const float*)d_in[0];
  const float* qkvw  = (const float*)d_in[1];
  const float* qkvb  = (const float*)d_in[2];
  const float* projw = (const float*)d_in[3];
  const float* projb = (const float*)d_in[4];
  const float* btab  = (const float*)d_in[5];
  const float* n1w   = (const float*)d_in[6];
  const float* n1b   = (const float*)d_in[7];
  const float* n2w   = (const float*)d_in[8];
  const float* n2b   = (const float*)d_in[9];
  const float* fc1w  = (const float*)d_in[10];
  const float* fc1b  = (const float*)d_in[11];
  const float* fc2w  = (const float*)d_in[12];
  const float* fc2b  = (const float*)d_in[13];
  const int* rel     = (const int*)d_in[14];

  char* ws = (char*)d_ws;
  size_t off = 0;
  auto alloc = [&](size_t bytes) -> char* {
    char* p = ws + off; off += (bytes + 255) & ~(size_t)255; return p;
  };
  u16* qkvwT   = (u16*)alloc((size_t)768 * 256 * 2);
  u16* projwT  = (u16*)alloc((size_t)256 * 256 * 2);
  u16* fc1wT   = (u16*)alloc((size_t)1024 * 256 * 2);
  u16* fc2wT   = (u16*)alloc((size_t)256 * 1024 * 2);
  float* biasm = (float*)alloc((size_t)NWIN * NHEADS * NW * NW * 4);
  u16* bufh    = (u16*)alloc((size_t)M_SZ * C_SZ * 2);   // h / attn-out / h2
  u16* x2b     = (u16*)alloc((size_t)M_SZ * C_SZ * 2);   // bf16 residual x2

  // dynamic chunking: 1 chunk if the full 196 MB scratch fits in ws, else 4
  const size_t full_scr = (size_t)M_SZ * HID_SZ * 2;
  const int nch = (ws_size >= off + full_scr + 256) ? 1 : 4;
  const int mch = M_SZ / nch;                 // rows per chunk
  const int wch = (B_SZ * NWIN) / nch;        // windows per chunk
  u16* scratch2 = (u16*)alloc((size_t)mch * HID_SZ * 2);

  transpose_kernel<<<(256 * 768 + 255) / 256, 256, 0, stream>>>(qkvw, qkvwT, 256, 768);
  transpose_kernel<<<(256 * 256 + 255) / 256, 256, 0, stream>>>(projw, projwT, 256, 256);
  transpose_kernel<<<(256 * 1024 + 255) / 256, 256, 0, stream>>>(fc1w, fc1wT, 256, 1024);
  transpose_kernel<<<(1024 * 256 + 255) / 256, 256, 0, stream>>>(fc2w, fc2wT, 1024, 256);
  bias_kernel<<<(NWIN * NHEADS * NW * NW + 255) / 256, 256, 0, stream>>>(btab, rel, biasm);

  ln1_kernel<<<M_SZ / 16, 256, 0, stream>>>(x, n1w, n1b, bufh);

  // qkv + attention per chunk, sharing scratch2
  for (int c = 0; c < nch; ++c) {
    const size_t roff = (size_t)c * mch;
    gemm_kernel<0><<<dim3(768 / BN, mch / BM), 256, 0, stream>>>(
        bufh + roff * C_SZ, qkvwT, qkvb, 768, 256, scratch2, nullptr, nullptr);
    attn_kernel<<<wch, 256, 0, stream>>>(scratch2, biasm, bufh + roff * C_SZ, c * wch);
  }

  // proj + un-roll + x residual -> bf16 x2 (full M: needs absolute rows)
  gemm_kernel<1><<<dim3(256 / BN, M_SZ / BM), 256, 0, stream>>>(
      bufh, projwT, projb, 256, 256, x2b, x, nullptr);

  // MLP per chunk; final fc2 writes f32 to d_out
  for (int q = 0; q < nch; ++q) {
    const size_t roff = (size_t)q * mch;
    ln2_kernel<<<mch / 16, 256, 0, stream>>>(x2b + roff * C_SZ, n2w, n2b,
                                             bufh + roff * C_SZ);
    gemm_kernel<2><<<dim3(1024 / BN, mch / BM), 256, 0, stream>>>(
        bufh + roff * C_SZ, fc1wT, fc1b, 1024, 256, scratch2, nullptr, nullptr);
    gemm_kernel<3><<<dim3(256 / BN, mch / BM), 256, 0, stream>>>(
        scratch2, fc2wT, fc2b, 256, 1024, (float*)d_out + roff * C_SZ,
        nullptr, x2b + roff * C_SZ);
  }
}